// Round 9
// baseline (160.535 us; speedup 1.0000x reference)
//
#include <hip/hip_runtime.h>

typedef _Float16 f16;
typedef _Float16 f16x8 __attribute__((ext_vector_type(8)));
typedef float f32x16 __attribute__((ext_vector_type(16)));
typedef unsigned long long u64;

#define NB 5
#define DIN 100
#define NT 512
#define GRID 256
#define WSZ 256                  // samples per block-window
#define WF4 (WSZ * 25)           // float4s per window (400B/row = 25 f4)

// fragment ids: W1 = [ks0..6][mt0..1] -> 14, W2 -> 8, heads: q*16 + layer*8 + ks*2 + mt
#define FID_W2 14
#define FID_HD 22
#define NFID   (FID_HD + NB * 16)   // 102
#define NENT   (NFID * 64)          // 6528 f16x8 entries

// A-frag layout (32x32x16): lane l holds W[k = 16*ks + 8*(l>>5) + e][feat = 32*mt + (l&31)]
__global__ __launch_bounds__(256)
void prepack_kernel(const float* __restrict__ dW1, const float* __restrict__ dW2,
                    const float* __restrict__ hw1, const float* __restrict__ hw2,
                    f16x8* __restrict__ pw)
{
    int E = blockIdx.x * 256 + threadIdx.x;
    if (E >= NENT) return;
    int lane = E & 63, fid = E >> 6;
    const float* src; int ks, mt, kmax;
    if (fid < FID_W2)      { int f = fid;          ks = f >> 1; mt = f & 1; src = dW1; kmax = 100; }
    else if (fid < FID_HD) { int f = fid - FID_W2; ks = f >> 1; mt = f & 1; src = dW2; kmax = 64; }
    else {
        int f = fid - FID_HD; int q = f >> 4; int r = f & 15;
        int layer = r >> 3; int rr = r & 7; ks = rr >> 1; mt = rr & 1;
        src = (layer ? hw2 : hw1) + q * 4096; kmax = 64;
    }
    f16x8 v;
    #pragma unroll
    for (int e = 0; e < 8; ++e) {
        int k = 16 * ks + 8 * (lane >> 5) + e;
        int m = 32 * mt + (lane & 31);
        v[e] = (k < kmax) ? (f16)src[k * 64 + m] : (f16)0.f;
    }
    pw[E] = v;
}

__device__ __forceinline__ f32x16 mfma32(f16x8 a, f16x8 b, f32x16 c) {
    return __builtin_amdgcn_mfma_f32_32x32x16_f16(a, b, c, 0, 0, 0);
}
__device__ __forceinline__ f32x16 vzero() {
    f32x16 z;
    #pragma unroll
    for (int i = 0; i < 16; ++i) z[i] = 0.f;
    return z;
}
__device__ __forceinline__ unsigned pk2(float a, float b) {
    union { f16 h[2]; unsigned u; } z; z.h[0] = (f16)a; z.h[1] = (f16)b; return z.u;
}
__device__ __forceinline__ f16x8 frag4(unsigned a, unsigned b, unsigned c, unsigned d) {
    union { unsigned u[4]; f16x8 v; } z; z.u[0]=a; z.u[1]=b; z.u[2]=c; z.u[3]=d; return z.v;
}
__device__ __forceinline__ u64 packf4(float4 v) {
    union { f16 h[4]; u64 u; } z;
    z.h[0]=(f16)v.x; z.h[1]=(f16)v.y; z.h[2]=(f16)v.z; z.h[3]=(f16)v.w;
    return z.u;
}
// stage addressing: row stride 224 B (=7*32, row-closed under bit-4 XOR)
__device__ __forceinline__ int SB(int r, int b) { return (r * 224 + b) ^ ((r & 7) << 4); }

#define EPI8T(W, A, BIAS, TW, RT, OFF) { \
    const float4* bp_ = (const float4*)((BIAS) + (OFF)); \
    const float4* tp_ = (const float4*)((TW) + (OFF)); \
    float4 b0_=bp_[0], b1_=bp_[2], b2_=bp_[4], b3_=bp_[6]; \
    float4 t0_=tp_[0], t1_=tp_[2], t2_=tp_[4], t3_=tp_[6]; \
    W[0]=pk2(fmaxf(A[0]+b0_.x+(RT)*t0_.x,0.f), fmaxf(A[1]+b0_.y+(RT)*t0_.y,0.f)); \
    W[1]=pk2(fmaxf(A[2]+b0_.z+(RT)*t0_.z,0.f), fmaxf(A[3]+b0_.w+(RT)*t0_.w,0.f)); \
    W[2]=pk2(fmaxf(A[4]+b1_.x+(RT)*t1_.x,0.f), fmaxf(A[5]+b1_.y+(RT)*t1_.y,0.f)); \
    W[3]=pk2(fmaxf(A[6]+b1_.z+(RT)*t1_.z,0.f), fmaxf(A[7]+b1_.w+(RT)*t1_.w,0.f)); \
    W[4]=pk2(fmaxf(A[8]+b2_.x+(RT)*t2_.x,0.f), fmaxf(A[9]+b2_.y+(RT)*t2_.y,0.f)); \
    W[5]=pk2(fmaxf(A[10]+b2_.z+(RT)*t2_.z,0.f), fmaxf(A[11]+b2_.w+(RT)*t2_.w,0.f)); \
    W[6]=pk2(fmaxf(A[12]+b3_.x+(RT)*t3_.x,0.f), fmaxf(A[13]+b3_.y+(RT)*t3_.y,0.f)); \
    W[7]=pk2(fmaxf(A[14]+b3_.z+(RT)*t3_.z,0.f), fmaxf(A[15]+b3_.w+(RT)*t3_.w,0.f)); }

#define EPI8B(W, A, BIAS, OFF) { \
    const float4* bp_ = (const float4*)((BIAS) + (OFF)); \
    float4 b0_=bp_[0], b1_=bp_[2], b2_=bp_[4], b3_=bp_[6]; \
    W[0]=pk2(fmaxf(A[0]+b0_.x,0.f), fmaxf(A[1]+b0_.y,0.f)); \
    W[1]=pk2(fmaxf(A[2]+b0_.z,0.f), fmaxf(A[3]+b0_.w,0.f)); \
    W[2]=pk2(fmaxf(A[4]+b1_.x,0.f), fmaxf(A[5]+b1_.y,0.f)); \
    W[3]=pk2(fmaxf(A[6]+b1_.z,0.f), fmaxf(A[7]+b1_.w,0.f)); \
    W[4]=pk2(fmaxf(A[8]+b2_.x,0.f), fmaxf(A[9]+b2_.y,0.f)); \
    W[5]=pk2(fmaxf(A[10]+b2_.z,0.f), fmaxf(A[11]+b2_.w,0.f)); \
    W[6]=pk2(fmaxf(A[12]+b3_.x,0.f), fmaxf(A[13]+b3_.y,0.f)); \
    W[7]=pk2(fmaxf(A[14]+b3_.z,0.f), fmaxf(A[15]+b3_.w,0.f)); }

#define MKB(dst, Wm, jb) { \
    unsigned s0_=__shfl_xor(Wm[jb+0],32,64), s1_=__shfl_xor(Wm[jb+1],32,64); \
    unsigned s2_=__shfl_xor(Wm[jb+2],32,64), s3_=__shfl_xor(Wm[jb+3],32,64); \
    dst = frag4(lo ? Wm[jb+0] : s2_, lo ? Wm[jb+1] : s3_, \
                lo ? s0_ : Wm[jb+2], lo ? s1_ : Wm[jb+3]); }

#define ACC16(P, A, B2, T2, W3, RT, OFF) { \
    const float4* bb_=(const float4*)((B2)+(OFF)); const float4* tt_=(const float4*)((T2)+(OFF)); \
    const float4* ww_=(const float4*)((W3)+(OFF)); \
    float4 b0_=bb_[0],b1_=bb_[2],b2_=bb_[4],b3_=bb_[6]; \
    float4 t0_=tt_[0],t1_=tt_[2],t2_=tt_[4],t3_=tt_[6]; \
    float4 w0_=ww_[0],w1_=ww_[2],w2_=ww_[4],w3_=ww_[6]; \
    P += fmaxf(A[0]+b0_.x+(RT)*t0_.x,0.f)*w0_.x + fmaxf(A[1]+b0_.y+(RT)*t0_.y,0.f)*w0_.y \
       + fmaxf(A[2]+b0_.z+(RT)*t0_.z,0.f)*w0_.z + fmaxf(A[3]+b0_.w+(RT)*t0_.w,0.f)*w0_.w \
       + fmaxf(A[4]+b1_.x+(RT)*t1_.x,0.f)*w1_.x + fmaxf(A[5]+b1_.y+(RT)*t1_.y,0.f)*w1_.y \
       + fmaxf(A[6]+b1_.z+(RT)*t1_.z,0.f)*w1_.z + fmaxf(A[7]+b1_.w+(RT)*t1_.w,0.f)*w1_.w \
       + fmaxf(A[8]+b2_.x+(RT)*t2_.x,0.f)*w2_.x + fmaxf(A[9]+b2_.y+(RT)*t2_.y,0.f)*w2_.y \
       + fmaxf(A[10]+b2_.z+(RT)*t2_.z,0.f)*w2_.z + fmaxf(A[11]+b2_.w+(RT)*t2_.w,0.f)*w2_.w \
       + fmaxf(A[12]+b3_.x+(RT)*t3_.x,0.f)*w3_.x + fmaxf(A[13]+b3_.y+(RT)*t3_.y,0.f)*w3_.y \
       + fmaxf(A[14]+b3_.z+(RT)*t3_.z,0.f)*w3_.z + fmaxf(A[15]+b3_.w+(RT)*t3_.w,0.f)*w3_.w; }

__global__ __launch_bounds__(NT, 2)
void drnet_main(const float* __restrict__ t, const float* __restrict__ x,
                const float* __restrict__ db1, const float* __restrict__ db2,
                const float* __restrict__ hb1, const float* __restrict__ htw1,
                const float* __restrict__ hb2, const float* __restrict__ htw2,
                const float* __restrict__ hw3, const float* __restrict__ htw3,
                const float* __restrict__ hb3,
                const f16x8* __restrict__ pw,
                float* __restrict__ out, int N, int NWIN)
{
    __shared__ __align__(16) unsigned char sxs[WSZ * 224];      // 57,344 B f16 stage (swizzled)
    __shared__ __align__(16) f16x8 sHD[NB * 16 * 64];           // 81,920 B head frags
    __shared__ __align__(16) f16x8 sW2[8 * 64];                 //  8,192 B trunk-L2 frags
    __shared__ __align__(16) float sb1f[64], sb2f[64];
    __shared__ __align__(16) float shb1[NB*64], shw1t[NB*64], shb2[NB*64], shw2t[NB*64], sw3f[NB*64];
    __shared__ float shtw3[NB], shb3[NB];
    __shared__ unsigned short ssrt[8][64];                      // per-wave own sort copy
    __shared__ float sstv[8][64];
    __shared__ float sout[WSZ];

    const int tid = threadIdx.x;
    const int lane = tid & 63;
    const int wv = tid >> 6;
    const int p = wv >> 1;          // wave-pair id: shares a 64-row sub-window
    const int h = wv & 1;           // which sorted half this wave computes
    const int hi = lane >> 5;
    const int sm = lane & 31;
    const bool lo = (hi == 0);

    // ---- LDS init (cooperative) ----
    for (int idx = tid; idx < NB*16*64; idx += NT)
        ((float4*)sHD)[idx] = ((const float4*)(pw + FID_HD*64))[idx];
    for (int idx = tid; idx < 8*64; idx += NT)
        ((float4*)sW2)[idx] = ((const float4*)(pw + FID_W2*64))[idx];
    for (int q = tid; q < 64; q += NT) { sb1f[q] = db1[q]; sb2f[q] = db2[q]; }
    for (int q = tid; q < NB*64; q += NT) {
        shb1[q] = hb1[q]; shw1t[q] = htw1[q];
        shb2[q] = hb2[q]; shw2t[q] = htw2[q];
        sw3f[q] = hw3[q];
    }
    if (tid < NB) { shtw3[tid] = htw3[tid]; shb3[tid] = hb3[tid]; }

    // W1 trunk frags resident in 56 VGPRs (loaded once; never reloaded -> no vmcnt pollution)
    f16x8 w1f[14];
    #pragma unroll
    for (int u = 0; u < 14; ++u) w1f[u] = pw[u * 64 + lane];

    // wave-local ballot sort of the pair's 64-sample sub-window (both pair-waves compute identically)
    auto sortw = [&](int Wn, float tv) {
        const long long i0 = (long long)Wn * WSZ + p * 64 + lane;
        const int qme = (i0 < (long long)N) ? min((int)(tv * 5.0f), NB - 1) : NB;
        const u64 lowm = (1ull << lane) - 1ull;
        int pos = 0;
        #pragma unroll
        for (int b = 0; b <= NB; ++b) {
            u64 mb = __ballot(qme == b);
            int ca = __popcll(mb), cb = __popcll(mb & lowm);
            pos += (b < qme) ? ca : ((b == qme) ? cb : 0);
        }
        ssrt[wv][pos] = (unsigned short)(lane | (qme << 8));
        sstv[wv][pos] = tv;
        __asm__ volatile("s_waitcnt lgkmcnt(0)" ::: "memory");
    };

    const size_t XMAX = (size_t)N * 25 - 1;      // last valid float4 index in x

    // ---- prologue: sort + stage window W0 ----
    int W = blockIdx.x;
    {
        float t0 = t[min((size_t)W * WSZ + p * 64 + lane, (size_t)(N - 1))];
        sortw(W, t0);
    }
    float tnext;
    {
        float4 rawP[13];
        const size_t base4 = (size_t)W * WF4;
        #pragma unroll
        for (int j = 0; j < 13; ++j) {
            int f = min(tid + NT * j, WF4 - 1);
            rawP[j] = ((const float4*)x)[min(base4 + (size_t)f, XMAX)];
        }
        tnext = t[min(((size_t)W + GRID) * WSZ + p * 64 + lane, (size_t)(N - 1))];
        #pragma unroll
        for (int j = 0; j < 13; ++j) {
            int f = min(tid + NT * j, WF4 - 1);
            int row = f / 25, c4 = f % 25;
            *(u64*)(sxs + SB(row, c4 * 8)) = packf4(rawP[j]);
        }
    }
    __syncthreads();

    // ---- main loop: one 32-sample tile per wave per window ----
    #pragma unroll 1
    for (; W < NWIN; W += GRID) {
        const int WN = W + GRID;

        // 1. descriptors + frag-read of window W from LDS stage
        const unsigned short pkme = ssrt[wv][h * 32 + sm];
        const int li = pkme & 63, rq = pkme >> 8;
        const float rt = sstv[wv][h * 32 + sm];
        const int qlo = ssrt[wv][h * 32] >> 8;
        const int qhi0 = ssrt[wv][h * 32 + 31] >> 8;
        const int row = p * 64 + li;

        f16x8 xb[7];
        #pragma unroll
        for (int ks = 0; ks < 7; ++ks)
            xb[ks] = *(const f16x8*)(sxs + SB(row, ks * 32 + hi * 16));
        {   // mask tail: k>=100 must be zero (cols 100..111 are unwritten garbage)
            union { f16x8 v; unsigned u[4]; } z; z.v = xb[6];
            const unsigned m0 = lo ? 0xFFFFFFFFu : 0u;
            z.u[0] &= m0; z.u[1] &= m0; z.u[2] = 0u; z.u[3] = 0u;
            xb[6] = z.v;
        }
        __asm__ volatile("s_waitcnt lgkmcnt(0)" ::: "memory");
        __builtin_amdgcn_sched_barrier(0);

        // 3. issue stage group A for WN (coalesced stream; stays in flight through trunk)
        float4 rawA[7];
        {
            const size_t base4 = (size_t)WN * WF4;
            #pragma unroll
            for (int j = 0; j < 7; ++j) {
                int f = min(tid + NT * j, WF4 - 1);
                rawA[j] = ((const float4*)x)[min(base4 + (size_t)f, XMAX)];
            }
        }
        // 2. barrier #1: all waves done reading stage(W)
        __syncthreads();

        // 4. sort WN (consumes tnext via counted vmcnt; A stays in flight) + 5. prefetch t(W+2G)
        sortw(WN, tnext);
        tnext = t[min(((size_t)W + 2 * GRID) * WSZ + p * 64 + lane, (size_t)(N - 1))];
        __builtin_amdgcn_sched_barrier(0);

        // 6. trunk compute (W1 regs, W2 LDS)
        f16x8 g0, g1, g2, g3;
        if (qlo < NB) {
            f32x16 a0 = vzero(), a1 = vzero();
            #pragma unroll
            for (int ks = 0; ks < 7; ++ks) {
                a0 = mfma32(w1f[ks * 2 + 0], xb[ks], a0);
                a1 = mfma32(w1f[ks * 2 + 1], xb[ks], a1);
            }
            unsigned WA[8], WB[8];
            EPI8B(WA, a0, sb1f, 4 * hi);
            EPI8B(WB, a1, sb1f, 32 + 4 * hi);
            f16x8 hb0, hb1_, hb2_, hb3_;
            MKB(hb0, WA, 0); MKB(hb1_, WA, 4); MKB(hb2_, WB, 0); MKB(hb3_, WB, 4);

            f32x16 c0 = vzero(), c1 = vzero();
            c0 = mfma32(sW2[0*64+lane], hb0, c0);  c1 = mfma32(sW2[1*64+lane], hb0, c1);
            c0 = mfma32(sW2[2*64+lane], hb1_, c0); c1 = mfma32(sW2[3*64+lane], hb1_, c1);
            c0 = mfma32(sW2[4*64+lane], hb2_, c0); c1 = mfma32(sW2[5*64+lane], hb2_, c1);
            c0 = mfma32(sW2[6*64+lane], hb3_, c0); c1 = mfma32(sW2[7*64+lane], hb3_, c1);
            unsigned UA[8], UB[8];
            EPI8B(UA, c0, sb2f, 4 * hi);
            EPI8B(UB, c1, sb2f, 32 + 4 * hi);
            MKB(g0, UA, 0); MKB(g1, UA, 4); MKB(g2, UB, 0); MKB(g3, UB, 4);
        }
        __builtin_amdgcn_sched_barrier(0);

        // 7. convert+write A (after barrier #1 -> safe); issue B (in flight through heads)
        float4 rawB[6];
        {
            #pragma unroll
            for (int j = 0; j < 7; ++j) {
                int f = min(tid + NT * j, WF4 - 1);
                int r2 = f / 25, c4 = f % 25;
                *(u64*)(sxs + SB(r2, c4 * 8)) = packf4(rawA[j]);
            }
            const size_t base4 = (size_t)WN * WF4;
            #pragma unroll
            for (int j = 0; j < 6; ++j) {
                int f = min(tid + NT * (7 + j), WF4 - 1);
                rawB[j] = ((const float4*)x)[min(base4 + (size_t)f, XMAX)];
            }
        }
        __builtin_amdgcn_sched_barrier(0);

        // 8. head compute (heads from LDS; q-loop usually 2-3 iterations)
        if (qlo < NB) {
            const int qhi = min(qhi0, NB - 1);
            #pragma unroll 1
            for (int q = qlo; q <= qhi; ++q) {
                const f16x8* ph = sHD + q * 16 * 64;
                f32x16 d0 = vzero(), d1 = vzero();
                d0 = mfma32(ph[0*64+lane], g0, d0);  d1 = mfma32(ph[1*64+lane], g0, d1);
                d0 = mfma32(ph[2*64+lane], g1, d0);  d1 = mfma32(ph[3*64+lane], g1, d1);
                d0 = mfma32(ph[4*64+lane], g2, d0);  d1 = mfma32(ph[5*64+lane], g2, d1);
                d0 = mfma32(ph[6*64+lane], g3, d0);  d1 = mfma32(ph[7*64+lane], g3, d1);
                unsigned VA[8], VB[8];
                EPI8T(VA, d0, shb1 + q*64, shw1t + q*64, rt, 4 * hi);
                EPI8T(VB, d1, shb1 + q*64, shw1t + q*64, rt, 32 + 4 * hi);
                f16x8 e0, e1, e2, e3;
                MKB(e0, VA, 0); MKB(e1, VA, 4); MKB(e2, VB, 0); MKB(e3, VB, 4);

                f32x16 f0 = vzero(), f1 = vzero();
                f0 = mfma32(ph[8*64+lane],  e0, f0);  f1 = mfma32(ph[9*64+lane],  e0, f1);
                f0 = mfma32(ph[10*64+lane], e1, f0);  f1 = mfma32(ph[11*64+lane], e1, f1);
                f0 = mfma32(ph[12*64+lane], e2, f0);  f1 = mfma32(ph[13*64+lane], e2, f1);
                f0 = mfma32(ph[14*64+lane], e3, f0);  f1 = mfma32(ph[15*64+lane], e3, f1);

                float part = 0.f;
                ACC16(part, f0, shb2 + q*64, shw2t + q*64, sw3f + q*64, rt, 4 * hi);
                ACC16(part, f1, shb2 + q*64, shw2t + q*64, sw3f + q*64, rt, 32 + 4 * hi);
                part += __shfl_xor(part, 32, 64);
                if (lo && rq == q)
                    sout[p * 64 + li] = part + rt * shtw3[q] + shb3[q];
            }
        }
        __builtin_amdgcn_sched_barrier(0);

        // 9. convert+write B
        #pragma unroll
        for (int j = 0; j < 6; ++j) {
            int f = min(tid + NT * (7 + j), WF4 - 1);
            int r2 = f / 25, c4 = f % 25;
            *(u64*)(sxs + SB(r2, c4 * 8)) = packf4(rawB[j]);
        }

        // 10. barrier #2: stage(WN) complete, sout complete
        __syncthreads();

        // 11. coalesced flush of window W
        if (tid < WSZ) {
            const size_t ig = (size_t)W * WSZ + tid;
            if (ig < (size_t)N) out[ig] = sout[tid];
        }
    }
}

extern "C" void kernel_launch(void* const* d_in, const int* in_sizes, int n_in,
                              void* d_out, int out_size, void* d_ws, size_t ws_size,
                              hipStream_t stream) {
    const float* t    = (const float*)d_in[0];
    const float* x    = (const float*)d_in[1];
    const float* dW1  = (const float*)d_in[2];
    const float* db1  = (const float*)d_in[3];
    const float* dW2  = (const float*)d_in[4];
    const float* db2  = (const float*)d_in[5];
    const float* hw1  = (const float*)d_in[6];
    const float* htw1 = (const float*)d_in[7];
    const float* hb1  = (const float*)d_in[8];
    const float* hw2  = (const float*)d_in[9];
    const float* htw2 = (const float*)d_in[10];
    const float* hb2  = (const float*)d_in[11];
    const float* hw3  = (const float*)d_in[12];
    const float* htw3 = (const float*)d_in[13];
    const float* hb3  = (const float*)d_in[14];
    float* out = (float*)d_out;

    const int N = in_sizes[0];
    const int NWIN = (N + WSZ - 1) / WSZ;
    f16x8* pw = (f16x8*)d_ws;   // NENT * 16 B = 104,448 B

    prepack_kernel<<<(NENT + 255) / 256, 256, 0, stream>>>(dW1, dW2, hw1, hw2, pw);
    drnet_main<<<GRID, NT, 0, stream>>>(t, x, db1, db2, hb1, htw1, hb2, htw2,
                                        hw3, htw3, hb3, pw, out, N, NWIN);
}

// Round 10
// 151.352 us; speedup vs baseline: 1.0607x; 1.0607x over previous
//
#include <hip/hip_runtime.h>

typedef _Float16 f16;
typedef _Float16 f16x8 __attribute__((ext_vector_type(8)));
typedef float f32x16 __attribute__((ext_vector_type(16)));
typedef unsigned long long u64;

#define NB 5
#define DIN 100
#define NT 512
#define GRID 256
#define NWAVES (GRID * 8)

// Homogeneous-coordinate weight fragments (bias/t folded into extra K rows):
//  W1ext[112][64]: rows<100 = dW1, row100 = db1       -> fids 0..13  (ks0..6 x mt0..1)
//  W2ext[80][64] : rows<64  = dW2, row64  = db2       -> fids 14..23 (ks0..4 x mt0..1)
//  heads, per q (base 24 + q*25):
//    L1ext[80][64]: <64 hw1, 64 hb1, 65 htw1          -> +0..9
//    L2ext[80][64]: <64 hw2, 64 hb2, 65 htw2          -> +10..19
//    L3ext[80][32]: col0: <64 hw3, 64 hb3, 65 htw3    -> +20..24 (single mt)
#define FID_W2 14
#define FID_HD 24
#define NFID   (FID_HD + NB * 25)    // 149
#define NENT   (NFID * 64)           // 9536 f16x8 entries = 152,576 B

// A-frag layout (32x32x16, r7-verified): lane l holds W[k = 16*ks + 8*(l>>5) + e][32*mt + (l&31)]
__global__ __launch_bounds__(256)
void prepack_kernel(const float* __restrict__ dW1, const float* __restrict__ db1,
                    const float* __restrict__ dW2, const float* __restrict__ db2,
                    const float* __restrict__ hw1, const float* __restrict__ htw1, const float* __restrict__ hb1,
                    const float* __restrict__ hw2, const float* __restrict__ htw2, const float* __restrict__ hb2,
                    const float* __restrict__ hw3, const float* __restrict__ htw3, const float* __restrict__ hb3,
                    f16x8* __restrict__ pw)
{
    int E = blockIdx.x * 256 + threadIdx.x;
    if (E >= NENT) return;
    const int lane = E & 63, fid = E >> 6;
    const int hi8 = (lane >> 5) * 8, m = lane & 31;
    f16x8 v;
    if (fid < FID_W2) {
        int ks = fid >> 1, mm = (fid & 1) * 32 + m;
        #pragma unroll
        for (int e = 0; e < 8; ++e) {
            int k = 16 * ks + hi8 + e;
            float val = (k < 100) ? dW1[k * 64 + mm] : (k == 100 ? db1[mm] : 0.f);
            v[e] = (f16)val;
        }
    } else if (fid < FID_HD) {
        int f = fid - FID_W2;
        int ks = f >> 1, mm = (f & 1) * 32 + m;
        #pragma unroll
        for (int e = 0; e < 8; ++e) {
            int k = 16 * ks + hi8 + e;
            float val = (k < 64) ? dW2[k * 64 + mm] : (k == 64 ? db2[mm] : 0.f);
            v[e] = (f16)val;
        }
    } else {
        int f = fid - FID_HD, q = f / 25, r = f % 25;
        if (r < 20) {
            int layer = r / 10, rr = r % 10;
            int ks = rr >> 1, mm = (rr & 1) * 32 + m;
            const float* W = layer ? hw2 : hw1;
            const float* B = layer ? hb2 : hb1;
            const float* T = layer ? htw2 : htw1;
            #pragma unroll
            for (int e = 0; e < 8; ++e) {
                int k = 16 * ks + hi8 + e;
                float val = (k < 64) ? W[q * 4096 + k * 64 + mm]
                          : (k == 64 ? B[q * 64 + mm]
                          : (k == 65 ? T[q * 64 + mm] : 0.f));
                v[e] = (f16)val;
            }
        } else {
            int ks = r - 20;
            #pragma unroll
            for (int e = 0; e < 8; ++e) {
                int k = 16 * ks + hi8 + e;
                float val = 0.f;
                if (m == 0)
                    val = (k < 64) ? hw3[q * 64 + k]
                        : (k == 64 ? hb3[q] : (k == 65 ? htw3[q] : 0.f));
                v[e] = (f16)val;
            }
        }
    }
    pw[E] = v;
}

__device__ __forceinline__ f32x16 mfma32(f16x8 a, f16x8 b, f32x16 c) {
    return __builtin_amdgcn_mfma_f32_32x32x16_f16(a, b, c, 0, 0, 0);
}
__device__ __forceinline__ f32x16 vzero() {
    f32x16 z;
    #pragma unroll
    for (int i = 0; i < 16; ++i) z[i] = 0.f;
    return z;
}
__device__ __forceinline__ unsigned pk2(float a, float b) {
    union { f16 h[2]; unsigned u; } z; z.h[0] = (f16)a; z.h[1] = (f16)b; return z.u;
}
__device__ __forceinline__ f16x8 frag4(unsigned a, unsigned b, unsigned c, unsigned d) {
    union { unsigned u[4]; f16x8 v; } z; z.u[0]=a; z.u[1]=b; z.u[2]=c; z.u[3]=d; return z.v;
}

// relu + pack only (bias/t are folded into the MFMA via homogeneous rows)
#define EPIR(W, A) { \
    W[0]=pk2(fmaxf(A[0],0.f), fmaxf(A[1],0.f)); \
    W[1]=pk2(fmaxf(A[2],0.f), fmaxf(A[3],0.f)); \
    W[2]=pk2(fmaxf(A[4],0.f), fmaxf(A[5],0.f)); \
    W[3]=pk2(fmaxf(A[6],0.f), fmaxf(A[7],0.f)); \
    W[4]=pk2(fmaxf(A[8],0.f), fmaxf(A[9],0.f)); \
    W[5]=pk2(fmaxf(A[10],0.f),fmaxf(A[11],0.f)); \
    W[6]=pk2(fmaxf(A[12],0.f),fmaxf(A[13],0.f)); \
    W[7]=pk2(fmaxf(A[14],0.f),fmaxf(A[15],0.f)); }

// assemble next layer's B-frag for one k-step (r7-verified; uses `lo` = lane<32)
#define MKB(dst, Wm, jb) { \
    unsigned s0_=__shfl_xor(Wm[jb+0],32,64), s1_=__shfl_xor(Wm[jb+1],32,64); \
    unsigned s2_=__shfl_xor(Wm[jb+2],32,64), s3_=__shfl_xor(Wm[jb+3],32,64); \
    dst = frag4(lo ? Wm[jb+0] : s2_, lo ? Wm[jb+1] : s3_, \
                lo ? s0_ : Wm[jb+2], lo ? s1_ : Wm[jb+3]); }

__global__ __launch_bounds__(NT, 2)
void drnet_main(const float* __restrict__ t, const float* __restrict__ x,
                const f16x8* __restrict__ pw,
                float* __restrict__ out, int N, int NG)
{
    __shared__ __align__(16) f16x8 swts[NENT];          // 152,576 B: all weight frags
    __shared__ unsigned short ssrt[8][64];
    __shared__ float sstv[8][64];
    __shared__ float sout[8][64];

    const int tid = threadIdx.x;
    const int lane = tid & 63;
    const int wv = tid >> 6;
    const int hi = lane >> 5;
    const int sm = lane & 31;
    const bool lo = (hi == 0);

    for (int p = tid; p < NENT; p += NT)
        ((float4*)swts)[p] = ((const float4*)pw)[p];
    __syncthreads();   // ONLY barrier; the main loop is fully wave-autonomous

    #define TF(fid) swts[(fid)*64 + lane]

    // trunk-L2 homogeneous frag: k=64 -> 1.0 (bias row)
    const f16x8 bfb = lo ? frag4(pk2(1.f, 0.f), 0u, 0u, 0u) : frag4(0u, 0u, 0u, 0u);

    // per-tile compute: 32 sorted samples; bias/t ride inside MFMA
    auto do_tile = [&](const f16x8* xb, f16x8 bft, int li, int rq, int qlo, int qhiR) {
        if (qlo >= NB) return;
        const int qhi = min(qhiR, NB - 1);

        // trunk L1 (bias at k=100, inside existing padding): 14 MFMA
        f32x16 a0 = vzero(), a1 = vzero();
        #pragma unroll
        for (int ks = 0; ks < 7; ++ks) {
            a0 = mfma32(TF(ks*2 + 0), xb[ks], a0);
            a1 = mfma32(TF(ks*2 + 1), xb[ks], a1);
        }
        unsigned WA[8], WB[8];
        EPIR(WA, a0); EPIR(WB, a1);
        f16x8 h0, h1_, h2_, h3_;
        MKB(h0, WA, 0); MKB(h1_, WA, 4); MKB(h2_, WB, 0); MKB(h3_, WB, 4);

        // trunk L2: K=80 (bias kstep via bfb): 10 MFMA
        f32x16 c0 = vzero(), c1 = vzero();
        c0 = mfma32(TF(FID_W2+0), h0, c0);  c1 = mfma32(TF(FID_W2+1), h0, c1);
        c0 = mfma32(TF(FID_W2+2), h1_, c0); c1 = mfma32(TF(FID_W2+3), h1_, c1);
        c0 = mfma32(TF(FID_W2+4), h2_, c0); c1 = mfma32(TF(FID_W2+5), h2_, c1);
        c0 = mfma32(TF(FID_W2+6), h3_, c0); c1 = mfma32(TF(FID_W2+7), h3_, c1);
        c0 = mfma32(TF(FID_W2+8), bfb, c0); c1 = mfma32(TF(FID_W2+9), bfb, c1);
        unsigned UA[8], UB[8];
        EPIR(UA, c0); EPIR(UB, c1);
        f16x8 g0, g1, g2, g3;
        MKB(g0, UA, 0); MKB(g1, UA, 4); MKB(g2, UB, 0); MKB(g3, UB, 4);

        #pragma unroll 1
        for (int q = qlo; q <= qhi; ++q) {
            const int hf = FID_HD + q * 25;
            // head L1: K=80 ([1,t] kstep via bft): 10 MFMA
            f32x16 d0 = vzero(), d1 = vzero();
            d0 = mfma32(TF(hf+0), g0, d0);  d1 = mfma32(TF(hf+1), g0, d1);
            d0 = mfma32(TF(hf+2), g1, d0);  d1 = mfma32(TF(hf+3), g1, d1);
            d0 = mfma32(TF(hf+4), g2, d0);  d1 = mfma32(TF(hf+5), g2, d1);
            d0 = mfma32(TF(hf+6), g3, d0);  d1 = mfma32(TF(hf+7), g3, d1);
            d0 = mfma32(TF(hf+8), bft, d0); d1 = mfma32(TF(hf+9), bft, d1);
            unsigned VA[8], VB[8];
            EPIR(VA, d0); EPIR(VB, d1);
            f16x8 e0, e1, e2, e3;
            MKB(e0, VA, 0); MKB(e1, VA, 4); MKB(e2, VB, 0); MKB(e3, VB, 4);

            // head L2: 10 MFMA
            f32x16 f0 = vzero(), f1 = vzero();
            f0 = mfma32(TF(hf+10), e0, f0);  f1 = mfma32(TF(hf+11), e0, f1);
            f0 = mfma32(TF(hf+12), e1, f0);  f1 = mfma32(TF(hf+13), e1, f1);
            f0 = mfma32(TF(hf+14), e2, f0);  f1 = mfma32(TF(hf+15), e2, f1);
            f0 = mfma32(TF(hf+16), e3, f0);  f1 = mfma32(TF(hf+17), e3, f1);
            f0 = mfma32(TF(hf+18), bft, f0); f1 = mfma32(TF(hf+19), bft, f1);
            unsigned YA[8], YB[8];
            EPIR(YA, f0); EPIR(YB, f1);
            f16x8 z0, z1, z2, z3;
            MKB(z0, YA, 0); MKB(z1, YA, 4); MKB(z2, YB, 0); MKB(z3, YB, 4);

            // head L3 as MFMA column (w3 dot + hb3 + t*htw3): 5 MFMA; out = row0
            f32x16 o0 = vzero();
            o0 = mfma32(TF(hf+20), z0, o0);
            o0 = mfma32(TF(hf+21), z1, o0);
            o0 = mfma32(TF(hf+22), z2, o0);
            o0 = mfma32(TF(hf+23), z3, o0);
            o0 = mfma32(TF(hf+24), bft, o0);
            if (lo && rq == q)
                sout[wv][li] = o0[0];      // row0 = reg0, hi=0; col = lane = sample
        }
    };

    // wave-local ballot counting sort of one 64-sample window (r7-verified)
    auto sortw = [&](int gn, float tvn) {
        const int i0 = gn * 64 + lane;
        const int qme = (i0 < N) ? min((int)(tvn * 5.0f), NB - 1) : NB;
        const u64 lowm = (1ull << lane) - 1ull;
        int pos = 0;
        #pragma unroll
        for (int b = 0; b <= NB; ++b) {
            u64 mb = __ballot(qme == b);
            int ca = __popcll(mb), cb = __popcll(mb & lowm);
            pos += (b < qme) ? ca : ((b == qme) ? cb : 0);
        }
        ssrt[wv][pos] = (unsigned short)(lane | (qme << 8));
        sstv[wv][pos] = tvn;
        __asm__ volatile("s_waitcnt lgkmcnt(0)" ::: "memory");
    };

    auto issue_x = [&](float4* r, int gn, int li) {
        const float4* xp = (const float4*)(x + (size_t)min(gn * 64 + li, N - 1) * DIN);
        #pragma unroll
        for (int ks = 0; ks < 6; ++ks) { r[2*ks] = xp[4*ks + 2*hi]; r[2*ks+1] = xp[4*ks + 2*hi + 1]; }
        r[12] = lo ? xp[24] : make_float4(0.f, 0.f, 0.f, 0.f);
    };

    auto convert = [&](f16x8* xb, const float4* r) {
        #pragma unroll
        for (int ks = 0; ks < 6; ++ks)
            xb[ks] = frag4(pk2(r[2*ks].x, r[2*ks].y),   pk2(r[2*ks].z, r[2*ks].w),
                           pk2(r[2*ks+1].x, r[2*ks+1].y), pk2(r[2*ks+1].z, r[2*ks+1].w));
        // k=100 is the homogeneous 1.0 (bias row of W1ext); k>100 zero
        xb[6] = frag4(pk2(r[12].x, r[12].y), pk2(r[12].z, r[12].w),
                      lo ? pk2(1.0f, 0.f) : 0u, 0u);
    };

    const int gw = blockIdx.x * 8 + wv;
    const int S = NWAVES;

    float4 raw0[13], raw1[13];
    float treg = 0.f;
    int g = gw;
    if (g < NG) {
        treg = t[min(g * 64 + lane, N - 1)];
        sortw(g, treg);                                   // window g sorted
        { int li = ssrt[wv][sm] & 63; issue_x(raw0, g, li); }   // T0(g) in flight
        { int gn = g + S; treg = (gn < NG) ? t[min(gn * 64 + lane, N - 1)] : 0.f; }
    }

    // INVARIANT at loop top: ssrt/sstv = window g; raw0 = T0(g) in flight; treg = t(g+S)
    #pragma unroll 1
    for (; g < NG; g += S) {
        const unsigned short pk0 = ssrt[wv][sm], pk1 = ssrt[wv][32 + sm];
        const int li0 = pk0 & 63, rq0 = pk0 >> 8;
        const int li1 = pk1 & 63, rq1 = pk1 >> 8;
        const float rt0 = sstv[wv][sm], rt1 = sstv[wv][32 + sm];
        const int qlo0 = ssrt[wv][0]  >> 8, qh0 = ssrt[wv][31] >> 8;
        const int qlo1 = ssrt[wv][32] >> 8, qh1 = ssrt[wv][63] >> 8;
        const f16x8 bft0 = lo ? frag4(pk2(1.f, rt0), 0u, 0u, 0u) : frag4(0u, 0u, 0u, 0u);
        const f16x8 bft1 = lo ? frag4(pk2(1.f, rt1), 0u, 0u, 0u) : frag4(0u, 0u, 0u, 0u);

        issue_x(raw1, g, li1);                 // T1(g) loads join the queue first
        f16x8 xb0[7], xb1[7];
        convert(xb0, raw0);                    // waits raw0 only (raw1 stays in flight)
        __builtin_amdgcn_sched_barrier(0);     // pin: loads issued before tile0 compute
        do_tile(xb0, bft0, li0, rq0, qlo0, qh0);
        __builtin_amdgcn_sched_barrier(0);     // pin: raw1 wait not hoisted above tile0

        const bool last = (g + S >= NG);
        if (!last) {
            sortw(g + S, treg);                // next window's sort (t prefetched 1 window ago)
            { int gn2 = g + 2 * S; treg = (gn2 < NG) ? t[min(gn2 * 64 + lane, N - 1)] : 0.f; }
            { int li = ssrt[wv][sm] & 63; issue_x(raw0, g + S, li); }  // T0(g+S) in flight
            __builtin_amdgcn_sched_barrier(0); // pin: next-window loads issued before tile1
        }
        convert(xb1, raw1);                    // counted wait: raw0(next) stays in flight
        do_tile(xb1, bft1, li1, rq1, qlo1, qh1);

        __asm__ volatile("s_waitcnt lgkmcnt(0)" ::: "memory");
        const int ig = g * 64 + lane;
        if (ig < N) out[ig] = sout[wv][lane];  // coalesced flush
    }
    #undef TF
}

extern "C" void kernel_launch(void* const* d_in, const int* in_sizes, int n_in,
                              void* d_out, int out_size, void* d_ws, size_t ws_size,
                              hipStream_t stream) {
    const float* t    = (const float*)d_in[0];
    const float* x    = (const float*)d_in[1];
    const float* dW1  = (const float*)d_in[2];
    const float* db1  = (const float*)d_in[3];
    const float* dW2  = (const float*)d_in[4];
    const float* db2  = (const float*)d_in[5];
    const float* hw1  = (const float*)d_in[6];
    const float* htw1 = (const float*)d_in[7];
    const float* hb1  = (const float*)d_in[8];
    const float* hw2  = (const float*)d_in[9];
    const float* htw2 = (const float*)d_in[10];
    const float* hb2  = (const float*)d_in[11];
    const float* hw3  = (const float*)d_in[12];
    const float* htw3 = (const float*)d_in[13];
    const float* hb3  = (const float*)d_in[14];
    float* out = (float*)d_out;

    const int N = in_sizes[0];
    const int NG = (N + 63) / 64;
    f16x8* pw = (f16x8*)d_ws;   // NENT * 16 B = 152,576 B

    prepack_kernel<<<(NENT + 255) / 256, 256, 0, stream>>>(
        dW1, db1, dW2, db2, hw1, htw1, hb1, hw2, htw2, hb2, hw3, htw3, hb3, pw);
    drnet_main<<<GRID, NT, 0, stream>>>(t, x, pw, out, N, NG);
}